// Round 3
// baseline (692.139 us; speedup 1.0000x reference)
//
#include <hip/hip_runtime.h>
#include <cstdint>
#include <cstddef>

#define D_ 1024
#define S_ 2048
#define B_ 32

typedef float f32x4 __attribute__((ext_vector_type(4)));
typedef __bf16 v8bf __attribute__((ext_vector_type(8)));

__device__ __forceinline__ unsigned short f2bf_rne(float f) {
  unsigned int u = __float_as_uint(f);
  u = (u + 0x7FFFu + ((u >> 16) & 1u)) >> 16;
  return (unsigned short)u;
}

// pack two fp32 into packed bf16x2 (round-half-up) via byte-perm
__device__ __forceinline__ unsigned int bfpack(float f0, float f1) {
  unsigned int u0 = __float_as_uint(f0) + 0x8000u;
  unsigned int u1 = __float_as_uint(f1) + 0x8000u;
  return __builtin_amdgcn_perm(u1, u0, 0x07060302u);  // lo=hi16(u0), hi=hi16(u1)
}

__device__ __forceinline__ float tanh_fast(float x) {
  float ax = __builtin_fabsf(x);
  float e = __expf(2.0f * ax);
  float r = 1.0f - 2.0f * __builtin_amdgcn_rcpf(e + 1.0f);
  return __builtin_copysignf(r, x);
}

// ---------------- K0: fused prep ----------------
// blocks [0,1024): W_c fp32 -> bf16 ; blocks [1024,2048): tadd = x@W_in.T + b_c
__global__ void k_prep(const float* __restrict__ wc, unsigned short* __restrict__ wcb,
                       const float* __restrict__ x, const float* __restrict__ win,
                       const float* __restrict__ bc, float* __restrict__ tadd) {
  __shared__ float wl[D_];
  int t = threadIdx.x;
  if (blockIdx.x < 1024) {
    int e = blockIdx.x;
    float4 v = ((const float4*)(wc + (size_t)e * D_))[t];
    ushort4 o;
    o.x = f2bf_rne(v.x); o.y = f2bf_rne(v.y); o.z = f2bf_rne(v.z); o.w = f2bf_rne(v.w);
    ((ushort4*)(wcb + (size_t)e * D_))[t] = o;
    return;
  }
  int e = blockIdx.x - 1024;
  ((float4*)wl)[t] = ((const float4*)(win + (size_t)e * D_))[t];
  __syncthreads();
  int w = t >> 6, lane = t & 63;
  float bce = bc[e];
  for (int bb = w; bb < B_; bb += 4) {
    const float* xr = x + (size_t)bb * D_ + lane * 16;
    const float* wr = wl + lane * 16;
    float p = 0.f;
#pragma unroll
    for (int c = 0; c < 4; ++c) {
      float4 xv = ((const float4*)xr)[c];
      float4 wv = ((const float4*)wr)[c];
      p += xv.x * wv.x + xv.y * wv.y + xv.z * wv.z + xv.w * wv.w;
    }
#pragma unroll
    for (int off = 32; off; off >>= 1) p += __shfl_xor(p, off, 64);
    if (lane == 0) tadd[(size_t)bb * D_ + e] = p + bce;
  }
}

// ---------------- K2: fused scores GEMM, 256s x 256e tile, 8 waves, BK=64 ----------------
// 8-phase schedule (4 phases/K-tile, mh x ks quadrants), double-buffered 128 KiB LDS,
// XOR swizzle (chunk ^= row&7), B via pre-swizzled global_load_lds, A reg-staged
// fp32->bf16 issue-early/write-late (T14). launch_bounds(512,1): min-waves arg MUST be 1
// (round-1 used 2 -> 128-VGPR cap -> ~90 regs spilled -> 69 MB scratch traffic).
__global__ __launch_bounds__(512, 1) void k_scores(
    const float* __restrict__ ctx, const unsigned short* __restrict__ wcb,
    const float* __restrict__ tadd, const float* __restrict__ wv,
    float* __restrict__ part) {
  __shared__ unsigned short Ab[2][256 * 64];   // 2 x 32 KiB
  __shared__ unsigned short Bb[2][256 * 64];   // 2 x 32 KiB

  const int g = blockIdx.x;                    // 1024 blocks
  const int j2 = g >> 3;
  const int stile = ((g & 7) << 5) + (j2 >> 2);   // XCD-swizzled: 4 et-siblings per XCD
  const int et = j2 & 3;
  const int b = stile >> 3;
  const int s0 = (stile & 7) << 8;
  const int e0 = et << 8;

  const int t = threadIdx.x;
  const int w = t >> 6, lane = t & 63;
  const int wr = w >> 2, wc = w & 3;           // 2M x 4N wave grid
  const int m = lane & 15, q = lane >> 4;
  const int swq = q ^ (m & 7);                 // swizzled 16B-chunk for ks=0 frag reads
  const int wrb = wr << 7;                     // wave A-row base (0/128)
  const int wcbs = wc << 6;                    // wave B-row base (0/64/128/192)

  f32x4 acc[8][4];
#pragma unroll
  for (int i = 0; i < 8; ++i)
#pragma unroll
    for (int j = 0; j < 4; ++j) acc[i][j] = (f32x4){0.f, 0.f, 0.f, 0.f};

  // A staging role: per K-tile each thread loads 8x float4 (coalesced 256B row-segments),
  // rows jj*32 + (t>>4), fp32 cols (t&15)*4 within the 64-wide K-slab.
  const int ar = t >> 4;                       // 0..31
  const int ac = (t & 15) << 2;                // 0..60
  const float* agp = ctx + (((size_t)(b * S_ + s0)) << 10) + ac;
  const int chA = (t & 15) >> 1;               // logical 16B chunk 0..7
  const int a_in = (t & 1) << 2;               // ushort offset within chunk (0/4)

  // B staging role: per wave 4 issues x 8 rows, source chunk pre-swizzled so that
  // the linear LDS dest (base + lane*16) lands the swizzled layout (rule #21).
  const unsigned short* bgp = wcb + ((size_t)e0 << 10);
  const int brow = lane >> 3;                  // 0..7
  const int bsc = (lane & 7) ^ ((lane >> 3) & 7);

  f32x4 av[8];

  // ---- prologue: stage K-tile 0 into buffer 0
#pragma unroll
  for (int jj = 0; jj < 8; ++jj)
    av[jj] = *(const f32x4*)(agp + (((size_t)((jj << 5) + ar)) << 10));
#pragma unroll
  for (int i = 0; i < 4; ++i) {
    const int rb = (w << 5) + (i << 3);
    const unsigned short* gs = bgp + (((size_t)(rb + brow)) << 10) + (bsc << 3);
    __builtin_amdgcn_global_load_lds(
        (const __attribute__((address_space(1))) unsigned int*)gs,
        (__attribute__((address_space(3))) unsigned int*)(&Bb[0][rb << 6]), 16, 0, 0);
  }
#pragma unroll
  for (int jj = 0; jj < 8; ++jj) {
    const int row = (jj << 5) + ar;
    uint2 o;
    o.x = bfpack(av[jj][0], av[jj][1]);
    o.y = bfpack(av[jj][2], av[jj][3]);
    *(uint2*)(&Ab[0][(row << 6) + ((chA ^ (row & 7)) << 3) + a_in]) = o;
  }
  __syncthreads();

#pragma unroll 2
  for (int kt = 0; kt < 16; ++kt) {
    const int cur = kt & 1;
    const unsigned short* Ac = Ab[cur];
    const unsigned short* Bc = Bb[cur];
    const bool stage = (kt < 15);
    v8bf af[4], bfr[4];

    // ===== phase 1: (mh=0, ks=0) + issue all staging for kt+1
#pragma unroll
    for (int i = 0; i < 4; ++i)
      af[i] = *(const v8bf*)(Ac + ((wrb + (i << 4) + m) << 6) + (swq << 3));
#pragma unroll
    for (int j = 0; j < 4; ++j)
      bfr[j] = *(const v8bf*)(Bc + ((wcbs + (j << 4) + m) << 6) + (swq << 3));
    if (stage) {
      const float* ag2 = agp + ((kt + 1) << 6);
#pragma unroll
      for (int jj = 0; jj < 8; ++jj)
        av[jj] = *(const f32x4*)(ag2 + (((size_t)((jj << 5) + ar)) << 10));
      const unsigned short* bg2 = bgp + ((kt + 1) << 6);
#pragma unroll
      for (int i = 0; i < 4; ++i) {
        const int rb = (w << 5) + (i << 3);
        const unsigned short* gs = bg2 + (((size_t)(rb + brow)) << 10) + (bsc << 3);
        __builtin_amdgcn_global_load_lds(
            (const __attribute__((address_space(1))) unsigned int*)gs,
            (__attribute__((address_space(3))) unsigned int*)(&Bb[cur ^ 1][rb << 6]), 16, 0, 0);
      }
    }
    __builtin_amdgcn_s_barrier();
    __builtin_amdgcn_s_setprio(1);
#pragma unroll
    for (int i = 0; i < 4; ++i)
#pragma unroll
      for (int j = 0; j < 4; ++j)
        acc[i][j] = __builtin_amdgcn_mfma_f32_16x16x32_bf16(af[i], bfr[j], acc[i][j], 0, 0, 0);
    __builtin_amdgcn_s_setprio(0);
    __builtin_amdgcn_s_barrier();

    // ===== phase 2: (mh=1, ks=0), reuse B frags
#pragma unroll
    for (int i = 0; i < 4; ++i)
      af[i] = *(const v8bf*)(Ac + ((wrb + 64 + (i << 4) + m) << 6) + (swq << 3));
    __builtin_amdgcn_s_barrier();
    __builtin_amdgcn_s_setprio(1);
#pragma unroll
    for (int i = 0; i < 4; ++i)
#pragma unroll
      for (int j = 0; j < 4; ++j)
        acc[4 + i][j] = __builtin_amdgcn_mfma_f32_16x16x32_bf16(af[i], bfr[j], acc[4 + i][j], 0, 0, 0);
    __builtin_amdgcn_s_setprio(0);
    __builtin_amdgcn_s_barrier();

    // ===== phase 3: (mh=0, ks=1)
#pragma unroll
    for (int i = 0; i < 4; ++i)
      af[i] = *(const v8bf*)(Ac + ((wrb + (i << 4) + m) << 6) + ((swq ^ 4) << 3));
#pragma unroll
    for (int j = 0; j < 4; ++j)
      bfr[j] = *(const v8bf*)(Bc + ((wcbs + (j << 4) + m) << 6) + ((swq ^ 4) << 3));
    __builtin_amdgcn_s_barrier();
    __builtin_amdgcn_s_setprio(1);
#pragma unroll
    for (int i = 0; i < 4; ++i)
#pragma unroll
      for (int j = 0; j < 4; ++j)
        acc[i][j] = __builtin_amdgcn_mfma_f32_16x16x32_bf16(af[i], bfr[j], acc[i][j], 0, 0, 0);
    __builtin_amdgcn_s_setprio(0);
    __builtin_amdgcn_s_barrier();

    // ===== phase 4: (mh=1, ks=1) + A convert/write-late into next buffer
    if (stage) {
      unsigned short* Ad = Ab[cur ^ 1];
#pragma unroll
      for (int jj = 0; jj < 8; ++jj) {
        const int row = (jj << 5) + ar;
        uint2 o;
        o.x = bfpack(av[jj][0], av[jj][1]);
        o.y = bfpack(av[jj][2], av[jj][3]);
        *(uint2*)(&Ad[(row << 6) + ((chA ^ (row & 7)) << 3) + a_in]) = o;
      }
    }
#pragma unroll
    for (int i = 0; i < 4; ++i)
      af[i] = *(const v8bf*)(Ac + ((wrb + 64 + (i << 4) + m) << 6) + ((swq ^ 4) << 3));
    __builtin_amdgcn_s_barrier();
    __builtin_amdgcn_s_setprio(1);
#pragma unroll
    for (int i = 0; i < 4; ++i)
#pragma unroll
      for (int j = 0; j < 4; ++j)
        acc[4 + i][j] = __builtin_amdgcn_mfma_f32_16x16x32_bf16(af[i], bfr[j], acc[4 + i][j], 0, 0, 0);
    __builtin_amdgcn_s_setprio(0);
    __syncthreads();   // K-tile boundary: the only full fence (drains B DMA issued 4 phases ago)
  }

  // epilogue: tanh(acc + tadd[b,e]) * w_v[e], reduce over the wave's 64 e-cols
  float sp[8][4];
#pragma unroll
  for (int i = 0; i < 8; ++i)
#pragma unroll
    for (int r = 0; r < 4; ++r) sp[i][r] = 0.f;
#pragma unroll
  for (int j = 0; j < 4; ++j) {
    const int e = e0 + wcbs + (j << 4) + m;
    const float ta = tadd[((size_t)b << 10) + e];
    const float wve = wv[e];
#pragma unroll
    for (int i = 0; i < 8; ++i)
#pragma unroll
      for (int r = 0; r < 4; ++r)
        sp[i][r] += tanh_fast(acc[i][j][r] + ta) * wve;
  }
#pragma unroll
  for (int off = 1; off < 16; off <<= 1)
#pragma unroll
    for (int i = 0; i < 8; ++i)
#pragma unroll
      for (int r = 0; r < 4; ++r) sp[i][r] += __shfl_xor(sp[i][r], off, 64);
  if (m == 0) {
    const int slice = (et << 2) + wc;          // 16 partial e-slices
    float* dst = part + (((size_t)(slice * B_ + b)) << 11) + s0 + wrb + (q << 2);
#pragma unroll
    for (int i = 0; i < 8; ++i)
#pragma unroll
      for (int r = 0; r < 4; ++r) dst[(i << 4) + r] = sp[i][r];
  }
}

// ---------------- K3: sum 16 partial slices, softmax over S, write attn_w ----------------
__global__ void k_softmax(const float* __restrict__ part, float* __restrict__ attn) {
  __shared__ float red[4];
  int b = blockIdx.x, t = threadIdx.x;
  int w = t >> 6, lane = t & 63;
  float sc[8];
#pragma unroll
  for (int u = 0; u < 8; ++u) {
    int s = t + (u << 8);
    float v = 0.f;
#pragma unroll
    for (int p = 0; p < 16; ++p) v += part[((size_t)p * B_ + b) * S_ + s];
    sc[u] = v;
  }
  float mx = sc[0];
#pragma unroll
  for (int u = 1; u < 8; ++u) mx = fmaxf(mx, sc[u]);
#pragma unroll
  for (int off = 32; off; off >>= 1) mx = fmaxf(mx, __shfl_xor(mx, off, 64));
  if (lane == 0) red[w] = mx;
  __syncthreads();
  mx = fmaxf(fmaxf(red[0], red[1]), fmaxf(red[2], red[3]));
  float sum = 0.f;
#pragma unroll
  for (int u = 0; u < 8; ++u) { sc[u] = __expf(sc[u] - mx); sum += sc[u]; }
#pragma unroll
  for (int off = 32; off; off >>= 1) sum += __shfl_xor(sum, off, 64);
  __syncthreads();
  if (lane == 0) red[w] = sum;
  __syncthreads();
  sum = red[0] + red[1] + red[2] + red[3];
  float rv = 1.0f / sum;
#pragma unroll
  for (int u = 0; u < 8; ++u) attn[(size_t)b * S_ + t + (u << 8)] = sc[u] * rv;
}

// ---------------- K4: partial weighted sums, 64-row chunks, full-row coalesced ----------------
// grid = 32 b x 32 chunks; pw[chunk][b][d]
__global__ void k_weighted(const float* __restrict__ ctx, const float* __restrict__ attn,
                           float* __restrict__ pw) {
  __shared__ float al[64];
  int bid = blockIdx.x;
  int b = bid >> 5, c = bid & 31;
  int t = threadIdx.x;
  int s0 = c << 6;
  if (t < 64) al[t] = attn[(size_t)b * S_ + s0 + t];
  __syncthreads();
  f32x4 acc = {0.f, 0.f, 0.f, 0.f};
  const float* base = ctx + ((size_t)b * S_ + s0) * D_ + (t << 2);
#pragma unroll 8
  for (int s = 0; s < 64; ++s) {
    float wgt = al[s];
    float4 v = *(const float4*)(base + (size_t)s * D_);
    acc.x += wgt * v.x; acc.y += wgt * v.y; acc.z += wgt * v.z; acc.w += wgt * v.w;
  }
  *(f32x4*)(pw + ((size_t)(c * B_ + b)) * D_ + (t << 2)) = acc;
}

// ---------------- K4b: reduce the 32 chunk partials (widened grid) ----------------
__global__ void k_wred(const float* __restrict__ pw, float* __restrict__ wgt) {
  int g = blockIdx.x;
  int b = g >> 2;
  int d = ((g & 3) << 8) + threadIdx.x;
  float v = 0.f;
#pragma unroll
  for (int c = 0; c < 32; ++c) v += pw[((size_t)(c * B_ + b)) * D_ + d];
  wgt[(size_t)b * D_ + d] = v;
}

// ---------------- K5: h[b,j] = tanh( [weighted|x][b,:] . W_out[j,:] ) ----------------
__global__ void k_out(const float* __restrict__ wgt, const float* __restrict__ x,
                      const float* __restrict__ wo, float* __restrict__ out) {
  __shared__ float wl[2 * D_];
  int jrow = blockIdx.x, t = threadIdx.x;
#pragma unroll
  for (int u = 0; u < 2; ++u)
    ((float4*)wl)[t + (u << 8)] = ((const float4*)(wo + (size_t)jrow * 2 * D_))[t + (u << 8)];
  __syncthreads();
  int w = t >> 6, lane = t & 63;
  for (int bb = w; bb < B_; bb += 4) {
    const float* src = (lane < 32) ? (wgt + (size_t)bb * D_ + (lane << 5))
                                   : (x + (size_t)bb * D_ + ((lane - 32) << 5));
    const float* wr = wl + (lane << 5);
    float p = 0.f;
#pragma unroll
    for (int c = 0; c < 8; ++c) {
      float4 a = ((const float4*)src)[c];
      float4 ww = ((const float4*)wr)[c];
      p += a.x * ww.x + a.y * ww.y + a.z * ww.z + a.w * ww.w;
    }
#pragma unroll
    for (int off = 32; off; off >>= 1) p += __shfl_xor(p, off, 64);
    if (lane == 0) out[(size_t)bb * D_ + jrow] = tanh_fast(p);
  }
}

extern "C" void kernel_launch(void* const* d_in, const int* in_sizes, int n_in,
                              void* d_out, int out_size, void* d_ws, size_t ws_size,
                              hipStream_t stream) {
  const float* x   = (const float*)d_in[0];
  const float* ctx = (const float*)d_in[1];
  const float* win = (const float*)d_in[2];
  const float* wc  = (const float*)d_in[3];
  const float* bc  = (const float*)d_in[4];
  const float* wv  = (const float*)d_in[5];
  const float* wo  = (const float*)d_in[6];
  float* out = (float*)d_out;  // [0,32768): h_tilde, [32768,98304): attn_w

  char* ws = (char*)d_ws;
  float* tadd = (float*)ws;                              // 128 KiB
  float* pw   = (float*)(ws + 131072);                   // 4 MiB (doubles as part)
  float* part = pw;                                      // 16 x 32 x 2048 x 4B = 4 MiB
  float* wgt  = (float*)(ws + 131072 + 4194304);         // 128 KiB
  unsigned short* wcb = (unsigned short*)(ws + 131072 + 4194304 + 131072);  // 2 MiB

  k_prep    <<<2048, 256, 0, stream>>>(wc, wcb, x, win, bc, tadd);
  k_scores  <<<1024, 512, 0, stream>>>(ctx, wcb, tadd, wv, part);
  k_softmax <<<32,   256, 0, stream>>>(part, out + 32768);
  k_weighted<<<1024, 256, 0, stream>>>(ctx, out + 32768, pw);
  k_wred    <<<128,  256, 0, stream>>>(pw, wgt);
  k_out     <<<1024, 256, 0, stream>>>(wgt, x, wo, out);
}

// Round 4
// 614.568 us; speedup vs baseline: 1.1262x; 1.1262x over previous
//
#include <hip/hip_runtime.h>
#include <cstdint>
#include <cstddef>

#define D_ 1024
#define S_ 2048
#define B_ 32

typedef float f32x4 __attribute__((ext_vector_type(4)));
typedef __bf16 v8bf __attribute__((ext_vector_type(8)));

__device__ __forceinline__ unsigned short f2bf_rne(float f) {
  unsigned int u = __float_as_uint(f);
  u = (u + 0x7FFFu + ((u >> 16) & 1u)) >> 16;
  return (unsigned short)u;
}

// pack two fp32 into packed bf16x2 (round-half-up) via byte-perm
__device__ __forceinline__ unsigned int bfpack(float f0, float f1) {
  unsigned int u0 = __float_as_uint(f0) + 0x8000u;
  unsigned int u1 = __float_as_uint(f1) + 0x8000u;
  return __builtin_amdgcn_perm(u1, u0, 0x07060302u);  // lo=hi16(u0), hi=hi16(u1)
}

__device__ __forceinline__ float tanh_fast(float x) {
  float ax = __builtin_fabsf(x);
  float e = __expf(2.0f * ax);
  float r = 1.0f - 2.0f * __builtin_amdgcn_rcpf(e + 1.0f);
  return __builtin_copysignf(r, x);
}

// ---------------- K0: fused prep ----------------
// blocks [0,1024): W_c fp32 -> bf16 ; blocks [1024,2048): tadd = x@W_in.T + b_c
__global__ void k_prep(const float* __restrict__ wc, unsigned short* __restrict__ wcb,
                       const float* __restrict__ x, const float* __restrict__ win,
                       const float* __restrict__ bc, float* __restrict__ tadd) {
  __shared__ float wl[D_];
  int t = threadIdx.x;
  if (blockIdx.x < 1024) {
    int e = blockIdx.x;
    float4 v = ((const float4*)(wc + (size_t)e * D_))[t];
    ushort4 o;
    o.x = f2bf_rne(v.x); o.y = f2bf_rne(v.y); o.z = f2bf_rne(v.z); o.w = f2bf_rne(v.w);
    ((ushort4*)(wcb + (size_t)e * D_))[t] = o;
    return;
  }
  int e = blockIdx.x - 1024;
  ((float4*)wl)[t] = ((const float4*)(win + (size_t)e * D_))[t];
  __syncthreads();
  int w = t >> 6, lane = t & 63;
  float bce = bc[e];
  for (int bb = w; bb < B_; bb += 4) {
    const float* xr = x + (size_t)bb * D_ + lane * 16;
    const float* wr = wl + lane * 16;
    float p = 0.f;
#pragma unroll
    for (int c = 0; c < 4; ++c) {
      float4 xv = ((const float4*)xr)[c];
      float4 wv = ((const float4*)wr)[c];
      p += xv.x * wv.x + xv.y * wv.y + xv.z * wv.z + xv.w * wv.w;
    }
#pragma unroll
    for (int off = 32; off; off >>= 1) p += __shfl_xor(p, off, 64);
    if (lane == 0) tadd[(size_t)bb * D_ + e] = p + bce;
  }
}

// ---------------- K2: fused scores GEMM, 128s x 128e block, wave tile 64x64 ----------------
// Round-0 schedule (stage -> sync -> compute, 2 barriers/kt) with a smaller wave tile:
// acc 4x4 (64 AGPR) instead of 4x8 (128) -> ~150 unified regs -> 3 waves/SIMD ->
// 3 blocks/CU. The per-kt vmcnt(0) drain at the barrier is now hidden by TWO other
// resident blocks' compute (m97 regime) instead of one.
__global__ __launch_bounds__(256, 3) void k_scores(
    const float* __restrict__ ctx, const unsigned short* __restrict__ wcb,
    const float* __restrict__ tadd, const float* __restrict__ wv,
    float* __restrict__ part) {
  __shared__ unsigned short As[128 * 32];   // 8 KB
  __shared__ unsigned short Bs[128 * 32];   // 8 KB
  int g = blockIdx.x;                       // 4096 blocks
  int xcd = g & 7;
  int j = g >> 3;                           // [0,512)
  int stile = xcd * 64 + (j >> 3);          // 8 et-siblings of one stile per XCD
  int et = j & 7;
  int b = stile >> 4;
  int s0 = (stile & 15) << 7;
  int e0 = et << 7;
  int t = threadIdx.x;
  int w = t >> 6, lane = t & 63;

  f32x4 acc[4][4];
#pragma unroll
  for (int i = 0; i < 4; ++i)
#pragma unroll
    for (int jj = 0; jj < 4; ++jj) acc[i][jj] = (f32x4){0.f, 0.f, 0.f, 0.f};

  const int m = lane & 15, q = lane >> 4;
  const int ws_ = (w & 1) << 6;        // s-offset of wave: 0 or 64
  const int we_ = (w >> 1) << 6;       // e-offset of wave: 0 or 64

  const int brow = lane >> 2;          // B DMA: 16 rows per issue
  const int bcol = (lane & 3) << 3;    // 8 bf16 = 16B per lane
  const int arow = t >> 2;             // A: 4 thr/row, 64 rows per pass, 2 passes
  const int acol = (t & 3) << 3;       // 8 fp32 per thread -> 16B bf16 write

  const size_t ctx_base = ((size_t)b * S_ + s0) * D_;
  const size_t wc_base = (size_t)e0 * D_;

  for (int kt = 0; kt < 32; ++kt) {
    const int k0 = kt << 5;
    __syncthreads();
    // B tile: 128 rows via DMA, wave w covers rows [w*32, w*32+32), 2 issues
#pragma unroll
    for (int p = 0; p < 2; ++p) {
      int row = (w << 5) + (p << 4) + brow;
      const unsigned short* gb = wcb + wc_base + (size_t)row * D_ + k0 + bcol;
      unsigned short* lp = Bs + (((w << 5) + (p << 4)) << 5);
      __builtin_amdgcn_global_load_lds(
          (const __attribute__((address_space(1))) unsigned int*)gb,
          (__attribute__((address_space(3))) unsigned int*)lp, 16, 0, 0);
    }
    // A tile: 128 rows x 32 k fp32 -> bf16, conflict-clean 16B writes
#pragma unroll
    for (int p = 0; p < 2; ++p) {
      int row = (p << 6) + arow;
      const float* gp = ctx + ctx_base + (size_t)row * D_ + k0 + acol;
      float4 v0 = ((const float4*)gp)[0];
      float4 v1 = ((const float4*)gp)[1];
      uint4 o;
      o.x = bfpack(v0.x, v0.y); o.y = bfpack(v0.z, v0.w);
      o.z = bfpack(v1.x, v1.y); o.w = bfpack(v1.z, v1.w);
      *(uint4*)(As + (row << 5) + acol) = o;
    }
    __syncthreads();
    v8bf a[4], bf[4];
#pragma unroll
    for (int i = 0; i < 4; ++i)
      a[i] = *(const v8bf*)(As + ((ws_ + (i << 4) + m) << 5) + (q << 3));
#pragma unroll
    for (int jj = 0; jj < 4; ++jj)
      bf[jj] = *(const v8bf*)(Bs + ((we_ + (jj << 4) + m) << 5) + (q << 3));
#pragma unroll
    for (int i = 0; i < 4; ++i)
#pragma unroll
      for (int jj = 0; jj < 4; ++jj)
        acc[i][jj] = __builtin_amdgcn_mfma_f32_16x16x32_bf16(a[i], bf[jj], acc[i][jj], 0, 0, 0);
  }

  // epilogue: tanh(acc + tadd[b,e]) * w_v[e], reduce over the wave's 64 e-cols
  float sp[4][4];
#pragma unroll
  for (int i = 0; i < 4; ++i)
#pragma unroll
    for (int r = 0; r < 4; ++r) sp[i][r] = 0.f;
#pragma unroll
  for (int jj = 0; jj < 4; ++jj) {
    int e = e0 + we_ + (jj << 4) + m;
    float ta = tadd[(size_t)b * D_ + e];
    float wve = wv[e];
#pragma unroll
    for (int i = 0; i < 4; ++i)
#pragma unroll
      for (int r = 0; r < 4; ++r)
        sp[i][r] += tanh_fast(acc[i][jj][r] + ta) * wve;
  }
#pragma unroll
  for (int off = 1; off < 16; off <<= 1)
#pragma unroll
    for (int i = 0; i < 4; ++i)
#pragma unroll
      for (int r = 0; r < 4; ++r) sp[i][r] += __shfl_xor(sp[i][r], off, 64);
  if (m == 0) {
    int ps = (et << 1) + (w >> 1);           // 16 partial e-slices
    float* dst = part + ((size_t)ps * B_ + b) * S_ + s0 + ws_ + (q << 2);
#pragma unroll
    for (int i = 0; i < 4; ++i)
#pragma unroll
      for (int r = 0; r < 4; ++r) dst[(i << 4) + r] = sp[i][r];
  }
}

// ---------------- K3: sum 16 partial slices, softmax over S, write attn_w ----------------
__global__ void k_softmax(const float* __restrict__ part, float* __restrict__ attn) {
  __shared__ float red[4];
  int b = blockIdx.x, t = threadIdx.x;
  int w = t >> 6, lane = t & 63;
  float sc[8];
#pragma unroll
  for (int u = 0; u < 8; ++u) {
    int s = t + (u << 8);
    float v = 0.f;
#pragma unroll
    for (int p = 0; p < 16; ++p) v += part[((size_t)p * B_ + b) * S_ + s];
    sc[u] = v;
  }
  float mx = sc[0];
#pragma unroll
  for (int u = 1; u < 8; ++u) mx = fmaxf(mx, sc[u]);
#pragma unroll
  for (int off = 32; off; off >>= 1) mx = fmaxf(mx, __shfl_xor(mx, off, 64));
  if (lane == 0) red[w] = mx;
  __syncthreads();
  mx = fmaxf(fmaxf(red[0], red[1]), fmaxf(red[2], red[3]));
  float sum = 0.f;
#pragma unroll
  for (int u = 0; u < 8; ++u) { sc[u] = __expf(sc[u] - mx); sum += sc[u]; }
#pragma unroll
  for (int off = 32; off; off >>= 1) sum += __shfl_xor(sum, off, 64);
  __syncthreads();
  if (lane == 0) red[w] = sum;
  __syncthreads();
  sum = red[0] + red[1] + red[2] + red[3];
  float rv = 1.0f / sum;
#pragma unroll
  for (int u = 0; u < 8; ++u) attn[(size_t)b * S_ + t + (u << 8)] = sc[u] * rv;
}

// ---------------- K4: partial weighted sums, 64-row chunks, full-row coalesced ----------------
// grid = 32 b x 32 chunks; pw[chunk][b][d]
__global__ void k_weighted(const float* __restrict__ ctx, const float* __restrict__ attn,
                           float* __restrict__ pw) {
  __shared__ float al[64];
  int bid = blockIdx.x;
  int b = bid >> 5, c = bid & 31;
  int t = threadIdx.x;
  int s0 = c << 6;
  if (t < 64) al[t] = attn[(size_t)b * S_ + s0 + t];
  __syncthreads();
  f32x4 acc = {0.f, 0.f, 0.f, 0.f};
  const float* base = ctx + ((size_t)b * S_ + s0) * D_ + (t << 2);
#pragma unroll 8
  for (int s = 0; s < 64; ++s) {
    float wgt = al[s];
    float4 v = *(const float4*)(base + (size_t)s * D_);
    acc.x += wgt * v.x; acc.y += wgt * v.y; acc.z += wgt * v.z; acc.w += wgt * v.w;
  }
  *(f32x4*)(pw + ((size_t)(c * B_ + b)) * D_ + (t << 2)) = acc;
}

// ---------------- K4b: reduce the 32 chunk partials (widened grid) ----------------
__global__ void k_wred(const float* __restrict__ pw, float* __restrict__ wgt) {
  int g = blockIdx.x;
  int b = g >> 2;
  int d = ((g & 3) << 8) + threadIdx.x;
  float v = 0.f;
#pragma unroll
  for (int c = 0; c < 32; ++c) v += pw[((size_t)(c * B_ + b)) * D_ + d];
  wgt[(size_t)b * D_ + d] = v;
}

// ---------------- K5: h[b,j] = tanh( [weighted|x][b,:] . W_out[j,:] ) ----------------
__global__ void k_out(const float* __restrict__ wgt, const float* __restrict__ x,
                      const float* __restrict__ wo, float* __restrict__ out) {
  __shared__ float wl[2 * D_];
  int jrow = blockIdx.x, t = threadIdx.x;
#pragma unroll
  for (int u = 0; u < 2; ++u)
    ((float4*)wl)[t + (u << 8)] = ((const float4*)(wo + (size_t)jrow * 2 * D_))[t + (u << 8)];
  __syncthreads();
  int w = t >> 6, lane = t & 63;
  for (int bb = w; bb < B_; bb += 4) {
    const float* src = (lane < 32) ? (wgt + (size_t)bb * D_ + (lane << 5))
                                   : (x + (size_t)bb * D_ + ((lane - 32) << 5));
    const float* wr = wl + (lane << 5);
    float p = 0.f;
#pragma unroll
    for (int c = 0; c < 8; ++c) {
      float4 a = ((const float4*)src)[c];
      float4 ww = ((const float4*)wr)[c];
      p += a.x * ww.x + a.y * ww.y + a.z * ww.z + a.w * ww.w;
    }
#pragma unroll
    for (int off = 32; off; off >>= 1) p += __shfl_xor(p, off, 64);
    if (lane == 0) out[(size_t)bb * D_ + jrow] = tanh_fast(p);
  }
}

extern "C" void kernel_launch(void* const* d_in, const int* in_sizes, int n_in,
                              void* d_out, int out_size, void* d_ws, size_t ws_size,
                              hipStream_t stream) {
  const float* x   = (const float*)d_in[0];
  const float* ctx = (const float*)d_in[1];
  const float* win = (const float*)d_in[2];
  const float* wc  = (const float*)d_in[3];
  const float* bc  = (const float*)d_in[4];
  const float* wv  = (const float*)d_in[5];
  const float* wo  = (const float*)d_in[6];
  float* out = (float*)d_out;  // [0,32768): h_tilde, [32768,98304): attn_w

  char* ws = (char*)d_ws;
  float* tadd = (float*)ws;                              // 128 KiB
  float* pw   = (float*)(ws + 131072);                   // 4 MiB (doubles as part)
  float* part = pw;                                      // 16 x 32 x 2048 x 4B = 4 MiB
  float* wgt  = (float*)(ws + 131072 + 4194304);         // 128 KiB
  unsigned short* wcb = (unsigned short*)(ws + 131072 + 4194304 + 131072);  // 2 MiB

  k_prep    <<<2048, 256, 0, stream>>>(wc, wcb, x, win, bc, tadd);
  k_scores  <<<4096, 256, 0, stream>>>(ctx, wcb, tadd, wv, part);
  k_softmax <<<32,   256, 0, stream>>>(part, out + 32768);
  k_weighted<<<1024, 256, 0, stream>>>(ctx, out + 32768, pw);
  k_wred    <<<128,  256, 0, stream>>>(pw, wgt);
  k_out     <<<1024, 256, 0, stream>>>(wgt, x, wo, out);
}